// Round 1
// baseline (1376.347 us; speedup 1.0000x reference)
//
#include <hip/hip_runtime.h>
#include <hip/hip_bf16.h>

#define EMB 256
#define HD 128

// ---------- helpers ----------
__device__ __forceinline__ unsigned int encf(float f){
  unsigned int u = __float_as_uint(f);
  return (u & 0x80000000u) ? ~u : (u | 0x80000000u);
}
__device__ __forceinline__ float decf(unsigned int k){
  unsigned int u = (k & 0x80000000u) ? (k & 0x7fffffffu) : ~k;
  return __uint_as_float(u);
}
// edge_index may be int32 or int64 (little-endian, values < 2^31) — flag-selected
__device__ __forceinline__ int eidx(const int* __restrict__ p, int is64, long long k){
  return is64 ? p[2*k] : p[(int)k];
}

// ---------- dtype detect: int64 layout has zero high words at odd int32 slots ----------
__global__ void detect_kernel(const int* __restrict__ ei, int* __restrict__ flag){
  int z = (ei[1]==0) + (ei[3]==0) + (ei[5]==0) + (ei[7]==0);
  *flag = (z == 4) ? 1 : 0;
}

// ---------- fold W1 into Wkqv: Wcomb[256][768] = [Wq@W1q | (Wk/sqrt(hd))@W1k | Wv] ----------
// blockIdx.y = c in [0,256]; c==256 computes the bias row bcomb.
__global__ void prep_weights(const float* __restrict__ Wkqv, const float* __restrict__ bkqv,
                             const float* __restrict__ W1,
                             float* __restrict__ Wcomb, float* __restrict__ bcomb){
  int n = blockIdx.x * blockDim.x + threadIdx.x;   // 0..767
  int c = blockIdx.y;                              // 0..256
  if (n >= 768) return;
  const float rs = rsqrtf(128.0f);
  bool isBias = (c == 256);
  const float* arow = isBias ? bkqv : (Wkqv + (size_t)c*768);
  float val;
  if (n < 512){
    bool isQ = (n < 256);
    int nn = isQ ? n : (n - 256);
    int h = nn >> 7, d = nn & 127;
    int srcoff = isQ ? (h*128) : (256 + h*128);    // kqv column block
    int w1off  = isQ ? 128 : 0;                    // W1 row block (k first, q second)
    float s = 0.f;
    for (int t = 0; t < 128; ++t)
      s = fmaf(arow[srcoff + t], W1[(size_t)(w1off + t)*128 + d], s);
    val = isQ ? s : s * rs;
  } else {
    val = arow[512 + (n - 512)];                   // v passthrough
  }
  if (isBias) bcomb[n] = val; else Wcomb[(size_t)c*768 + n] = val;
}

// ---------- fp32 tiled GEMM: C = A[M,K]@B[K,N] + epilogue ----------
// MODE 0: C = AB + bias[n]
// MODE 1: C = relu(AB + deg[m]*bias[n]) + xres[m*N+n]
#define BM 128
#define BN 64
#define BK 16
template<int MODE>
__global__ __launch_bounds__(256) void gemm_kernel(
    const float* __restrict__ A, const float* __restrict__ B,
    const float* __restrict__ bias, float* __restrict__ C,
    int M, int N, int K,
    const int* __restrict__ deg, const float* __restrict__ xres)
{
  __shared__ float As[BK][BM];
  __shared__ float Bs[BK][BN];
  const int tid = threadIdx.x;
  const int tx = tid & 15;        // 4 output cols
  const int ty = tid >> 4;        // 8 output rows
  const int m0 = blockIdx.y * BM;
  const int n0 = blockIdx.x * BN;
  const int ar = tid >> 2, ac = (tid & 3) << 2;    // A tile: 64 rows x2, 4 k each
  const int br = tid >> 4, bc = (tid & 15) << 2;   // B tile: 16 rows, 4 n each
  float acc[8][4];
  #pragma unroll
  for (int u=0;u<8;++u){
    #pragma unroll
    for (int v=0;v<4;++v) acc[u][v]=0.f;
  }
  for (int k0 = 0; k0 < K; k0 += BK){
    #pragma unroll
    for (int rr = 0; rr < 2; ++rr){
      int r = ar + rr*64;
      float4 av = make_float4(0.f,0.f,0.f,0.f);
      if (m0 + r < M) av = *(const float4*)(A + (size_t)(m0+r)*K + k0 + ac);
      As[ac+0][r]=av.x; As[ac+1][r]=av.y; As[ac+2][r]=av.z; As[ac+3][r]=av.w;
    }
    *(float4*)(&Bs[br][bc]) = *(const float4*)(B + (size_t)(k0+br)*N + n0 + bc);
    __syncthreads();
    #pragma unroll
    for (int kk = 0; kk < BK; ++kk){
      float a8[8], b4[4];
      *(float4*)(a8)   = *(const float4*)(&As[kk][ty*8]);
      *(float4*)(a8+4) = *(const float4*)(&As[kk][ty*8+4]);
      *(float4*)(b4)   = *(const float4*)(&Bs[kk][tx*4]);
      #pragma unroll
      for (int u=0;u<8;++u){
        #pragma unroll
        for (int v=0;v<4;++v)
          acc[u][v] = fmaf(a8[u], b4[v], acc[u][v]);
      }
    }
    __syncthreads();
  }
  float bv0 = bias[n0+tx*4+0], bv1 = bias[n0+tx*4+1];
  float bv2 = bias[n0+tx*4+2], bv3 = bias[n0+tx*4+3];
  #pragma unroll
  for (int u=0;u<8;++u){
    int m = m0 + ty*8 + u;
    if (m >= M) continue;
    float4 o;
    if (MODE == 0){
      o.x = acc[u][0]+bv0; o.y = acc[u][1]+bv1; o.z = acc[u][2]+bv2; o.w = acc[u][3]+bv3;
    } else {
      float dg = (float)deg[m];
      const float4 xv = *(const float4*)(xres + (size_t)m*N + n0 + tx*4);
      o.x = fmaxf(acc[u][0]+dg*bv0,0.f)+xv.x;
      o.y = fmaxf(acc[u][1]+dg*bv1,0.f)+xv.y;
      o.z = fmaxf(acc[u][2]+dg*bv2,0.f)+xv.z;
      o.w = fmaxf(acc[u][3]+dg*bv3,0.f)+xv.w;
    }
    *(float4*)(C + (size_t)m*N + n0 + tx*4) = o;
  }
}

// ---------- per-edge attention score: one wave per edge, half-wave per head ----------
__global__ __launch_bounds__(256) void edge_score_kernel(
    const float* __restrict__ P, const int* __restrict__ ei,
    const float* __restrict__ b1, const float* __restrict__ W2, const float* __restrict__ b2,
    float* __restrict__ att, unsigned int* __restrict__ m_enc, int* __restrict__ deg,
    const int* __restrict__ flag, int E0, int Nn)
{
  int wave = blockIdx.x * (blockDim.x >> 6) + (threadIdx.x >> 6);
  int lane = threadIdx.x & 63;
  int E = 2*E0 + Nn;
  if (wave >= E) return;
  int is64 = *flag;
  int j, i;
  if (wave < E0){ j = eidx(ei,is64,wave); i = eidx(ei,is64,(long long)E0+wave); }
  else if (wave < 2*E0){ int e = wave - E0; i = eidx(ei,is64,e); j = eidx(ei,is64,(long long)E0+e); }
  else { i = j = wave - 2*E0; }
  i = min(max(i,0), Nn-1); j = min(max(j,0), Nn-1);
  int h = lane >> 5, l = lane & 31;
  int d = l * 4;
  const float4 qv  = *(const float4*)(P + (size_t)i*768 + h*128 + d);
  const float4 kv  = *(const float4*)(P + (size_t)j*768 + 256 + h*128 + d);
  const float4 b1v = *(const float4*)(b1 + d);
  const float4 w2v = *(const float4*)(W2 + d);
  float p0 = fmaxf(qv.x+kv.x+b1v.x, 0.f)*w2v.x
           + fmaxf(qv.y+kv.y+b1v.y, 0.f)*w2v.y
           + fmaxf(qv.z+kv.z+b1v.z, 0.f)*w2v.z
           + fmaxf(qv.w+kv.w+b1v.w, 0.f)*w2v.w;
  #pragma unroll
  for (int off = 16; off >= 1; off >>= 1)
    p0 += __shfl_xor(p0, off, 64);
  if (l == 0){
    float a = p0 + b2[0];
    att[(size_t)wave*2 + h] = a;
    atomicMax(m_enc + (size_t)i*2 + h, encf(a));
    if (h == 0) atomicAdd(deg + i, 1);
  }
}

// ---------- exp(a - m) and segment sum ----------
__global__ void edge_exp_kernel(const int* __restrict__ ei, const int* __restrict__ flag,
                                float* __restrict__ att, const unsigned int* __restrict__ m_enc,
                                float* __restrict__ s, int E0, int Nn){
  int t = blockIdx.x*blockDim.x + threadIdx.x;
  int E = 2*E0 + Nn;
  if (t >= 2*E) return;
  int e = t >> 1, h = t & 1;
  int is64 = *flag;
  int i;
  if (e < E0) i = eidx(ei,is64,(long long)E0+e);
  else if (e < 2*E0) i = eidx(ei,is64,e-E0);
  else i = e - 2*E0;
  i = min(max(i,0), Nn-1);
  float m = decf(m_enc[(size_t)i*2+h]);
  float ex = expf(att[t] - m);
  att[t] = ex;
  atomicAdd(s + (size_t)i*2+h, ex);
}

// ---------- alpha * v aggregation (atomic) ----------
__global__ __launch_bounds__(256) void aggregate_kernel(
    const float* __restrict__ P, const int* __restrict__ ei, const int* __restrict__ flag,
    const float* __restrict__ att, const float* __restrict__ s,
    float* __restrict__ agg, int E0, int Nn)
{
  int wave = blockIdx.x * (blockDim.x >> 6) + (threadIdx.x >> 6);
  int lane = threadIdx.x & 63;
  int E = 2*E0 + Nn;
  if (wave >= E) return;
  int is64 = *flag;
  int j, i;
  if (wave < E0){ j = eidx(ei,is64,wave); i = eidx(ei,is64,(long long)E0+wave); }
  else if (wave < 2*E0){ int e = wave - E0; i = eidx(ei,is64,e); j = eidx(ei,is64,(long long)E0+e); }
  else { i = j = wave - 2*E0; }
  i = min(max(i,0), Nn-1); j = min(max(j,0), Nn-1);
  int h = lane >> 5, l = lane & 31;
  int d = l * 4;
  float alpha = att[(size_t)wave*2 + h] / (s[(size_t)i*2+h] + 1e-16f);
  const float4 vv = *(const float4*)(P + (size_t)j*768 + 512 + h*128 + d);
  float* dst = agg + (size_t)i*256 + h*128 + d;
  atomicAdd(dst+0, alpha*vv.x);
  atomicAdd(dst+1, alpha*vv.y);
  atomicAdd(dst+2, alpha*vv.z);
  atomicAdd(dst+3, alpha*vv.w);
}

// ---------- launch ----------
extern "C" void kernel_launch(void* const* d_in, const int* in_sizes, int n_in,
                              void* d_out, int out_size, void* d_ws, size_t ws_size,
                              hipStream_t stream)
{
  const float* x     = (const float*)d_in[0];
  const int*   ei    = (const int*)d_in[1];
  const float* Wkqv  = (const float*)d_in[2];
  const float* bkqv  = (const float*)d_in[3];
  const float* W1    = (const float*)d_in[4];
  const float* b1    = (const float*)d_in[5];
  const float* W2    = (const float*)d_in[6];
  const float* b2    = (const float*)d_in[7];
  const float* Wout  = (const float*)d_in[8];
  const float* bout  = (const float*)d_in[9];
  float* out = (float*)d_out;

  const int N  = in_sizes[0] / EMB;   // 50000
  const int E0 = in_sizes[1] / 2;     // 100000
  const int E  = 2*E0 + N;            // 250000

  // workspace layout (fp32): ~209 MB
  float* Wcomb = (float*)d_ws;                         // 256*768
  float* bcomb = Wcomb + 256*768;                      // 768
  float* P     = bcomb + 768;                          // N*768  (qpart|kpart|v)
  float* agg   = P + (size_t)N*768;                    // N*256
  float* att   = agg + (size_t)N*256;                  // E*2
  unsigned int* m_enc = (unsigned int*)(att + (size_t)E*2); // N*2
  float* svec  = (float*)(m_enc + (size_t)N*2);        // N*2
  int* deg     = (int*)(svec + (size_t)N*2);           // N
  int* flag    = deg + N;                              // 1

  hipMemsetAsync(agg, 0, (size_t)N*256*sizeof(float), stream);
  hipMemsetAsync(m_enc, 0, ((size_t)N*4 + N + 1)*sizeof(int), stream); // m_enc,s,deg,flag

  detect_kernel<<<1,1,0,stream>>>(ei, flag);
  prep_weights<<<dim3(3,257),256,0,stream>>>(Wkqv, bkqv, W1, Wcomb, bcomb);

  {
    dim3 grid(768/BN, (N+BM-1)/BM);
    gemm_kernel<0><<<grid,256,0,stream>>>(x, Wcomb, bcomb, P, N, 768, 256, nullptr, nullptr);
  }
  {
    int blocks = (E + 3) / 4; // 4 waves per 256-thread block
    edge_score_kernel<<<blocks,256,0,stream>>>(P, ei, b1, W2, b2, att, m_enc, deg, flag, E0, N);
    edge_exp_kernel<<<(2*E+255)/256,256,0,stream>>>(ei, flag, att, m_enc, svec, E0, N);
    aggregate_kernel<<<blocks,256,0,stream>>>(P, ei, flag, att, svec, agg, E0, N);
  }
  {
    dim3 grid(EMB/BN, (N+BM-1)/BM);
    gemm_kernel<1><<<grid,256,0,stream>>>(agg, Wout, bout, out, N, EMB, 256, deg, x);
  }
}

// Round 2
// 665.608 us; speedup vs baseline: 2.0678x; 2.0678x over previous
//
#include <hip/hip_runtime.h>
#include <hip/hip_bf16.h>

#define EMB 256
#define HD 128

// ---------- helpers ----------
__device__ __forceinline__ unsigned int encf(float f){
  unsigned int u = __float_as_uint(f);
  return (u & 0x80000000u) ? ~u : (u | 0x80000000u);
}
__device__ __forceinline__ float decf(unsigned int k){
  unsigned int u = (k & 0x80000000u) ? (k & 0x7fffffffu) : ~k;
  return __uint_as_float(u);
}
// edge_index may be int32 or int64 (little-endian, values < 2^31) — flag-selected
__device__ __forceinline__ int eidx(const int* __restrict__ p, int is64, long long k){
  return is64 ? p[2*k] : p[(int)k];
}

// ---------- dtype detect: int64 layout has zero high words at odd int32 slots ----------
__global__ void detect_kernel(const int* __restrict__ ei, int* __restrict__ flag){
  int z = (ei[1]==0) + (ei[3]==0) + (ei[5]==0) + (ei[7]==0);
  *flag = (z == 4) ? 1 : 0;
}

// ---------- fold W1 into Wkqv: Wcomb[256][768] = [Wq@W1q | (Wk/sqrt(hd))@W1k | Wv] ----------
__global__ void prep_weights(const float* __restrict__ Wkqv, const float* __restrict__ bkqv,
                             const float* __restrict__ W1,
                             float* __restrict__ Wcomb, float* __restrict__ bcomb){
  int n = blockIdx.x * blockDim.x + threadIdx.x;   // 0..767
  int c = blockIdx.y;                              // 0..256
  if (n >= 768) return;
  const float rs = rsqrtf(128.0f);
  bool isBias = (c == 256);
  const float* arow = isBias ? bkqv : (Wkqv + (size_t)c*768);
  float val;
  if (n < 512){
    bool isQ = (n < 256);
    int nn = isQ ? n : (n - 256);
    int h = nn >> 7, d = nn & 127;
    int srcoff = isQ ? (h*128) : (256 + h*128);    // kqv column block
    int w1off  = isQ ? 128 : 0;                    // W1 row block (k first, q second)
    float s = 0.f;
    for (int t = 0; t < 128; ++t)
      s = fmaf(arow[srcoff + t], W1[(size_t)(w1off + t)*128 + d], s);
    val = isQ ? s : s * rs;
  } else {
    val = arow[512 + (n - 512)];                   // v passthrough
  }
  if (isBias) bcomb[n] = val; else Wcomb[(size_t)c*768 + n] = val;
}

// ---------- fp32 tiled GEMM: C = A[M,K]@B[K,N] + epilogue ----------
// MODE 0: C = AB + bias[n]
// MODE 1: C = relu(AB + deg[m]*bias[n]) + xres[m*N+n]
#define BM 128
#define BN 64
#define BK 16
template<int MODE>
__global__ __launch_bounds__(256) void gemm_kernel(
    const float* __restrict__ A, const float* __restrict__ B,
    const float* __restrict__ bias, float* __restrict__ C,
    int M, int N, int K,
    const int* __restrict__ deg, const float* __restrict__ xres)
{
  __shared__ float As[BK][BM];
  __shared__ float Bs[BK][BN];
  const int tid = threadIdx.x;
  const int tx = tid & 15;        // 4 output cols
  const int ty = tid >> 4;        // 8 output rows
  const int m0 = blockIdx.y * BM;
  const int n0 = blockIdx.x * BN;
  const int ar = tid >> 2, ac = (tid & 3) << 2;    // A tile: 64 rows x2, 4 k each
  const int br = tid >> 4, bc = (tid & 15) << 2;   // B tile: 16 rows, 4 n each
  float acc[8][4];
  #pragma unroll
  for (int u=0;u<8;++u){
    #pragma unroll
    for (int v=0;v<4;++v) acc[u][v]=0.f;
  }
  for (int k0 = 0; k0 < K; k0 += BK){
    #pragma unroll
    for (int rr = 0; rr < 2; ++rr){
      int r = ar + rr*64;
      float4 av = make_float4(0.f,0.f,0.f,0.f);
      if (m0 + r < M) av = *(const float4*)(A + (size_t)(m0+r)*K + k0 + ac);
      As[ac+0][r]=av.x; As[ac+1][r]=av.y; As[ac+2][r]=av.z; As[ac+3][r]=av.w;
    }
    *(float4*)(&Bs[br][bc]) = *(const float4*)(B + (size_t)(k0+br)*N + n0 + bc);
    __syncthreads();
    #pragma unroll
    for (int kk = 0; kk < BK; ++kk){
      float a8[8], b4[4];
      *(float4*)(a8)   = *(const float4*)(&As[kk][ty*8]);
      *(float4*)(a8+4) = *(const float4*)(&As[kk][ty*8+4]);
      *(float4*)(b4)   = *(const float4*)(&Bs[kk][tx*4]);
      #pragma unroll
      for (int u=0;u<8;++u){
        #pragma unroll
        for (int v=0;v<4;++v)
          acc[u][v] = fmaf(a8[u], b4[v], acc[u][v]);
      }
    }
    __syncthreads();
  }
  float bv0 = bias[n0+tx*4+0], bv1 = bias[n0+tx*4+1];
  float bv2 = bias[n0+tx*4+2], bv3 = bias[n0+tx*4+3];
  #pragma unroll
  for (int u=0;u<8;++u){
    int m = m0 + ty*8 + u;
    if (m >= M) continue;
    float4 o;
    if (MODE == 0){
      o.x = acc[u][0]+bv0; o.y = acc[u][1]+bv1; o.z = acc[u][2]+bv2; o.w = acc[u][3]+bv3;
    } else {
      float dg = (float)deg[m];
      const float4 xv = *(const float4*)(xres + (size_t)m*N + n0 + tx*4);
      o.x = fmaxf(acc[u][0]+dg*bv0,0.f)+xv.x;
      o.y = fmaxf(acc[u][1]+dg*bv1,0.f)+xv.y;
      o.z = fmaxf(acc[u][2]+dg*bv2,0.f)+xv.z;
      o.w = fmaxf(acc[u][3]+dg*bv3,0.f)+xv.w;
    }
    *(float4*)(C + (size_t)m*N + n0 + tx*4) = o;
  }
}

// ---------- per-edge attention score: one wave per edge, half-wave per head ----------
__global__ __launch_bounds__(256) void edge_score_kernel(
    const float* __restrict__ P, const int* __restrict__ ei,
    const float* __restrict__ b1, const float* __restrict__ W2, const float* __restrict__ b2,
    float* __restrict__ att, unsigned int* __restrict__ m_enc, int* __restrict__ deg,
    const int* __restrict__ flag, int E0, int Nn)
{
  int wave = blockIdx.x * (blockDim.x >> 6) + (threadIdx.x >> 6);
  int lane = threadIdx.x & 63;
  int E = 2*E0 + Nn;
  if (wave >= E) return;
  int is64 = *flag;
  int j, i;
  if (wave < E0){ j = eidx(ei,is64,wave); i = eidx(ei,is64,(long long)E0+wave); }
  else if (wave < 2*E0){ int e = wave - E0; i = eidx(ei,is64,e); j = eidx(ei,is64,(long long)E0+e); }
  else { i = j = wave - 2*E0; }
  i = min(max(i,0), Nn-1); j = min(max(j,0), Nn-1);
  int h = lane >> 5, l = lane & 31;
  int d = l * 4;
  const float4 qv  = *(const float4*)(P + (size_t)i*768 + h*128 + d);
  const float4 kv  = *(const float4*)(P + (size_t)j*768 + 256 + h*128 + d);
  const float4 b1v = *(const float4*)(b1 + d);
  const float4 w2v = *(const float4*)(W2 + d);
  float p0 = fmaxf(qv.x+kv.x+b1v.x, 0.f)*w2v.x
           + fmaxf(qv.y+kv.y+b1v.y, 0.f)*w2v.y
           + fmaxf(qv.z+kv.z+b1v.z, 0.f)*w2v.z
           + fmaxf(qv.w+kv.w+b1v.w, 0.f)*w2v.w;
  #pragma unroll
  for (int off = 16; off >= 1; off >>= 1)
    p0 += __shfl_xor(p0, off, 64);
  if (l == 0){
    float a = p0 + b2[0];
    att[(size_t)wave*2 + h] = a;
    atomicMax(m_enc + (size_t)i*2 + h, encf(a));
    if (h == 0) atomicAdd(deg + i, 1);
  }
}

// ---------- exp(a - m) and segment sum ----------
__global__ void edge_exp_kernel(const int* __restrict__ ei, const int* __restrict__ flag,
                                float* __restrict__ att, const unsigned int* __restrict__ m_enc,
                                float* __restrict__ s, int E0, int Nn){
  int t = blockIdx.x*blockDim.x + threadIdx.x;
  int E = 2*E0 + Nn;
  if (t >= 2*E) return;
  int e = t >> 1, h = t & 1;
  int is64 = *flag;
  int i;
  if (e < E0) i = eidx(ei,is64,(long long)E0+e);
  else if (e < 2*E0) i = eidx(ei,is64,e-E0);
  else i = e - 2*E0;
  i = min(max(i,0), Nn-1);
  float m = decf(m_enc[(size_t)i*2+h]);
  float ex = expf(att[t] - m);
  att[t] = ex;
  atomicAdd(s + (size_t)i*2+h, ex);
}

// ---------- exclusive prefix scan of deg -> off[0..N], single workgroup ----------
__global__ __launch_bounds__(1024) void scan_kernel(const int* __restrict__ deg,
                                                    int* __restrict__ off, int N){
  __shared__ int wsum[16];
  __shared__ int carry_s;
  int tid = threadIdx.x, lane = tid & 63, w = tid >> 6;
  if (tid == 0) carry_s = 0;
  __syncthreads();
  for (int base = 0; base < N; base += 1024){
    int carry = carry_s;
    int v = (base + tid < N) ? deg[base + tid] : 0;
    int incl = v;
    #pragma unroll
    for (int o = 1; o < 64; o <<= 1){
      int t = __shfl_up(incl, o, 64);
      if (lane >= o) incl += t;
    }
    if (lane == 63) wsum[w] = incl;
    __syncthreads();
    if (w == 0 && lane < 16){
      int sv = wsum[lane];
      #pragma unroll
      for (int o = 1; o < 16; o <<= 1){
        int t = __shfl_up(sv, o, 64);
        if (lane >= o) sv += t;
      }
      wsum[lane] = sv;
    }
    __syncthreads();
    int wpref = (w == 0) ? 0 : wsum[w-1];
    if (base + tid < N) off[base + tid] = carry + wpref + incl - v;
    __syncthreads();
    if (tid == 1023) carry_s = carry + wsum[15];
    __syncthreads();
  }
  if (threadIdx.x == 0) off[N] = carry_s;
}

// ---------- scatter edges into CSR buckets with final alpha ----------
__global__ void scatter_kernel(const int* __restrict__ ei, const int* __restrict__ flag,
                               const float* __restrict__ att, const float* __restrict__ s,
                               const int* __restrict__ off, int* __restrict__ cursor,
                               int* __restrict__ bj, float2* __restrict__ bw, int E0, int Nn){
  int e = blockIdx.x*blockDim.x + threadIdx.x;
  int E = 2*E0 + Nn;
  if (e >= E) return;
  int is64 = *flag;
  int j, i;
  if (e < E0){ j = eidx(ei,is64,e); i = eidx(ei,is64,(long long)E0+e); }
  else if (e < 2*E0){ int t = e - E0; i = eidx(ei,is64,t); j = eidx(ei,is64,(long long)E0+t); }
  else { i = j = e - 2*E0; }
  i = min(max(i,0), Nn-1); j = min(max(j,0), Nn-1);
  float w0 = att[(size_t)e*2+0] / (s[(size_t)i*2+0] + 1e-16f);
  float w1 = att[(size_t)e*2+1] / (s[(size_t)i*2+1] + 1e-16f);
  int pos = atomicAdd(cursor + i, 1);
  int slot = off[i] + pos;
  bj[slot] = j;
  bw[slot] = make_float2(w0, w1);
}

// ---------- gather: one wave per destination node, no atomics ----------
__global__ __launch_bounds__(256) void gather_kernel(
    const float* __restrict__ P, const int* __restrict__ bj, const float2* __restrict__ bw,
    const int* __restrict__ off, float* __restrict__ agg, int Nn)
{
  int i = blockIdx.x * (blockDim.x >> 6) + (threadIdx.x >> 6);
  if (i >= Nn) return;
  int lane = threadIdx.x & 63;
  int h = lane >> 5, d = (lane & 31) * 4;
  int s0 = off[i], s1 = off[i+1];
  float4 acc = make_float4(0.f,0.f,0.f,0.f);
  for (int t = s0; t < s1; ++t){
    int j = bj[t];
    float2 w = bw[t];
    float a = h ? w.y : w.x;
    const float4 vv = *(const float4*)(P + (size_t)j*768 + 512 + h*128 + d);
    acc.x = fmaf(a, vv.x, acc.x);
    acc.y = fmaf(a, vv.y, acc.y);
    acc.z = fmaf(a, vv.z, acc.z);
    acc.w = fmaf(a, vv.w, acc.w);
  }
  *(float4*)(agg + (size_t)i*256 + h*128 + d) = acc;
}

// ---------- launch ----------
extern "C" void kernel_launch(void* const* d_in, const int* in_sizes, int n_in,
                              void* d_out, int out_size, void* d_ws, size_t ws_size,
                              hipStream_t stream)
{
  const float* x     = (const float*)d_in[0];
  const int*   ei    = (const int*)d_in[1];
  const float* Wkqv  = (const float*)d_in[2];
  const float* bkqv  = (const float*)d_in[3];
  const float* W1    = (const float*)d_in[4];
  const float* b1    = (const float*)d_in[5];
  const float* W2    = (const float*)d_in[6];
  const float* b2    = (const float*)d_in[7];
  const float* Wout  = (const float*)d_in[8];
  const float* bout  = (const float*)d_in[9];
  float* out = (float*)d_out;

  const int N  = in_sizes[0] / EMB;   // 50000
  const int E0 = in_sizes[1] / 2;     // 100000
  const int E  = 2*E0 + N;            // 250000

  // workspace layout (fp32 words)
  float* Wcomb = (float*)d_ws;                         // 256*768
  float* bcomb = Wcomb + 256*768;                      // 768
  float* P     = bcomb + 768;                          // N*768  (qpart|kpart|v)
  float* agg   = P + (size_t)N*768;                    // N*256
  float* att   = agg + (size_t)N*256;                  // E*2
  unsigned int* m_enc = (unsigned int*)(att + (size_t)E*2); // N*2
  float* svec  = (float*)(m_enc + (size_t)N*2);        // N*2
  int* deg     = (int*)(svec + (size_t)N*2);           // N
  int* flag    = deg + N;                              // 1
  int* off     = flag + 1;                             // N+1
  int* cursor  = off + (N+1);                          // N
  int* bj      = cursor + N;                           // E
  float2* bw   = (float2*)(bj + E);                    // E float2 (8B-aligned: word offset even)

  // zero: m_enc, svec, deg, flag (contiguous) and cursor
  hipMemsetAsync(m_enc, 0, ((size_t)N*4 + N + 1)*sizeof(int), stream);
  hipMemsetAsync(cursor, 0, (size_t)N*sizeof(int), stream);

  detect_kernel<<<1,1,0,stream>>>(ei, flag);
  prep_weights<<<dim3(3,257),256,0,stream>>>(Wkqv, bkqv, W1, Wcomb, bcomb);

  {
    dim3 grid(768/BN, (N+BM-1)/BM);
    gemm_kernel<0><<<grid,256,0,stream>>>(x, Wcomb, bcomb, P, N, 768, 256, nullptr, nullptr);
  }
  {
    int blocks = (E + 3) / 4; // 4 waves per 256-thread block
    edge_score_kernel<<<blocks,256,0,stream>>>(P, ei, b1, W2, b2, att, m_enc, deg, flag, E0, N);
    edge_exp_kernel<<<(2*E+255)/256,256,0,stream>>>(ei, flag, att, m_enc, svec, E0, N);
    scan_kernel<<<1,1024,0,stream>>>(deg, off, N);
    scatter_kernel<<<(E+255)/256,256,0,stream>>>(ei, flag, att, svec, off, cursor, bj, bw, E0, N);
    gather_kernel<<<(N+3)/4,256,0,stream>>>(P, bj, bw, off, agg, N);
  }
  {
    dim3 grid(EMB/BN, (N+BM-1)/BM);
    gemm_kernel<1><<<grid,256,0,stream>>>(agg, Wout, bout, out, N, EMB, 256, deg, x);
  }
}

// Round 3
// 440.283 us; speedup vs baseline: 3.1260x; 1.5118x over previous
//
#include <hip/hip_runtime.h>
#include <hip/hip_bf16.h>

#define EMB 256
#define HD 128

typedef __bf16 bf16_t;
typedef __attribute__((ext_vector_type(8))) __bf16 bf16x8;
typedef __attribute__((ext_vector_type(4))) __bf16 bf16x4;
typedef __attribute__((ext_vector_type(4))) float floatx4;

// ---------- helpers ----------
__device__ __forceinline__ unsigned int encf(float f){
  unsigned int u = __float_as_uint(f);
  return (u & 0x80000000u) ? ~u : (u | 0x80000000u);
}
__device__ __forceinline__ float decf(unsigned int k){
  unsigned int u = (k & 0x80000000u) ? (k & 0x7fffffffu) : ~k;
  return __uint_as_float(u);
}
__device__ __forceinline__ int eidx(const int* __restrict__ p, int is64, long long k){
  return is64 ? p[2*k] : p[(int)k];
}
// async global->LDS, 16B per lane; lptr is WAVE-UNIFORM base, data lands at lptr + lane*16
__device__ __forceinline__ void async_load16(const void* g, void* l){
  __builtin_amdgcn_global_load_lds(
      (const __attribute__((address_space(1))) unsigned int*)g,
      (__attribute__((address_space(3))) unsigned int*)l,
      16, 0, 0);
}

// ---------- dtype detect ----------
__global__ void detect_kernel(const int* __restrict__ ei, int* __restrict__ flag){
  int z = (ei[1]==0) + (ei[3]==0) + (ei[5]==0) + (ei[7]==0);
  *flag = (z == 4) ? 1 : 0;
}

// ---------- x -> bf16 ----------
__global__ void cvt_x_kernel(const float* __restrict__ x, bf16_t* __restrict__ xb, int n4){
  int t = blockIdx.x*blockDim.x + threadIdx.x;
  if (t >= n4) return;
  const float4 v = *(const float4*)(x + (size_t)t*4);
  bf16x4 o = { (bf16_t)v.x, (bf16_t)v.y, (bf16_t)v.z, (bf16_t)v.w };
  *(bf16x4*)(xb + (size_t)t*4) = o;
}

// ---------- fold W1 into Wkqv; emit TRANSPOSED bf16 WcombT[768][256] + fp32 bcomb[768] ----------
__global__ void prep_weights(const float* __restrict__ Wkqv, const float* __restrict__ bkqv,
                             const float* __restrict__ W1,
                             bf16_t* __restrict__ WcombT, float* __restrict__ bcomb){
  int n = blockIdx.x * blockDim.x + threadIdx.x;   // 0..767 (output col)
  int c = blockIdx.y;                              // 0..256 (k index; 256 = bias)
  if (n >= 768) return;
  const float rs = rsqrtf(128.0f);
  bool isBias = (c == 256);
  const float* arow = isBias ? bkqv : (Wkqv + (size_t)c*768);
  float val;
  if (n < 512){
    bool isQ = (n < 256);
    int nn = isQ ? n : (n - 256);
    int h = nn >> 7, d = nn & 127;
    int srcoff = isQ ? (h*128) : (256 + h*128);
    int w1off  = isQ ? 128 : 0;
    float s = 0.f;
    for (int t = 0; t < 128; ++t)
      s = fmaf(arow[srcoff + t], W1[(size_t)(w1off + t)*128 + d], s);
    val = isQ ? s : s * rs;
  } else {
    val = arow[512 + (n - 512)];
  }
  if (isBias) bcomb[n] = val;
  else        WcombT[(size_t)n*256 + c] = (bf16_t)val;
}

// ---------- Wout -> transposed bf16 WoutT[256][256] ----------
__global__ void prep_wout(const float* __restrict__ W, bf16_t* __restrict__ Wt){
  int t = blockIdx.x*blockDim.x + threadIdx.x;  // 65536
  int n = t & 255, c = t >> 8;
  Wt[(size_t)n*256 + c] = (bf16_t)W[(size_t)c*256 + n];
}

// ---------- bf16 MFMA GEMM: C = A[M,K] @ Bt[N,K]^T + epilogue ----------
// Tile 128x128x32, 4 waves, each wave 64x64 via 4x4 MFMA 16x16x32.
// LDS is FRAGMENT-ORDERED: frag f (16 rows x 32 k) = 64 chunks of 16B, chunk l holds
// row f*16+(l&15), k quad (l>>4)*8..+7. global_load_lds lands lane l at base+l*16.
// MODE 0: C = AB + bias[n]            MODE 1: C = relu(AB + deg[m]*bias[n]) + xres
template<int MODE>
__global__ __launch_bounds__(256) void mfma_gemm(
    const bf16_t* __restrict__ A, const bf16_t* __restrict__ Bt,
    const float* __restrict__ bias, float* __restrict__ C,
    int M, int N, int K,
    const int* __restrict__ deg, const float* __restrict__ xres)
{
  __shared__ bf16_t As[128*32];
  __shared__ bf16_t Bs[128*32];
  const int tid = threadIdx.x;
  const int wave = tid >> 6, lane = tid & 63;
  const int m0 = blockIdx.y * 128, n0 = blockIdx.x * 128;
  const int wm = (wave >> 1) * 64;       // wave's m offset in tile
  const int wn = (wave & 1) * 64;        // wave's n offset in tile
  const int row16 = lane & 15, quad = lane >> 4;

  floatx4 acc[4][4];
  #pragma unroll
  for (int a=0;a<4;++a)
    #pragma unroll
    for (int b=0;b<4;++b) acc[a][b] = (floatx4){0.f,0.f,0.f,0.f};

  for (int k0 = 0; k0 < K; k0 += 32){
    #pragma unroll
    for (int s = 0; s < 2; ++s){
      int f = wave*2 + s;
      int gm = m0 + f*16 + row16; gm = min(gm, M-1);
      async_load16(A  + (size_t)gm*K + k0 + quad*8, (char*)As + f*1024);
      int gn = n0 + f*16 + row16;          // N is a multiple of 128
      async_load16(Bt + (size_t)gn*K + k0 + quad*8, (char*)Bs + f*1024);
    }
    __syncthreads();
    bf16x8 af[4], bfr[4];
    #pragma unroll
    for (int t = 0; t < 4; ++t){
      af[t]  = *(const bf16x8*)((const char*)As + ((wm>>4)+t)*1024 + lane*16);
      bfr[t] = *(const bf16x8*)((const char*)Bs + ((wn>>4)+t)*1024 + lane*16);
    }
    #pragma unroll
    for (int mt=0;mt<4;++mt)
      #pragma unroll
      for (int nt=0;nt<4;++nt)
        acc[mt][nt] = __builtin_amdgcn_mfma_f32_16x16x32_bf16(af[mt], bfr[nt], acc[mt][nt], 0,0,0);
    __syncthreads();
  }

  // epilogue: C/D layout col=lane&15, row=quad*4+reg
  #pragma unroll
  for (int mt=0;mt<4;++mt){
    #pragma unroll
    for (int r=0;r<4;++r){
      int m = m0 + wm + mt*16 + quad*4 + r;
      if (m >= M) continue;
      float dg = (MODE==1) ? (float)deg[m] : 0.f;
      #pragma unroll
      for (int nt=0;nt<4;++nt){
        int n = n0 + wn + nt*16 + row16;
        float v = acc[mt][nt][r];
        if (MODE == 0){
          v += bias[n];
        } else {
          v = fmaxf(v + dg*bias[n], 0.f) + xres[(size_t)m*N + n];
        }
        C[(size_t)m*N + n] = v;
      }
    }
  }
}

// ---------- per-edge attention score ----------
__global__ __launch_bounds__(256) void edge_score_kernel(
    const float* __restrict__ P, const int* __restrict__ ei,
    const float* __restrict__ b1, const float* __restrict__ W2, const float* __restrict__ b2,
    float* __restrict__ att, unsigned int* __restrict__ m_enc, int* __restrict__ deg,
    const int* __restrict__ flag, int E0, int Nn)
{
  int wave = blockIdx.x * (blockDim.x >> 6) + (threadIdx.x >> 6);
  int lane = threadIdx.x & 63;
  int E = 2*E0 + Nn;
  if (wave >= E) return;
  int is64 = *flag;
  int j, i;
  if (wave < E0){ j = eidx(ei,is64,wave); i = eidx(ei,is64,(long long)E0+wave); }
  else if (wave < 2*E0){ int e = wave - E0; i = eidx(ei,is64,e); j = eidx(ei,is64,(long long)E0+e); }
  else { i = j = wave - 2*E0; }
  i = min(max(i,0), Nn-1); j = min(max(j,0), Nn-1);
  int h = lane >> 5, l = lane & 31;
  int d = l * 4;
  const float4 qv  = *(const float4*)(P + (size_t)i*768 + h*128 + d);
  const float4 kv  = *(const float4*)(P + (size_t)j*768 + 256 + h*128 + d);
  const float4 b1v = *(const float4*)(b1 + d);
  const float4 w2v = *(const float4*)(W2 + d);
  float p0 = fmaxf(qv.x+kv.x+b1v.x, 0.f)*w2v.x
           + fmaxf(qv.y+kv.y+b1v.y, 0.f)*w2v.y
           + fmaxf(qv.z+kv.z+b1v.z, 0.f)*w2v.z
           + fmaxf(qv.w+kv.w+b1v.w, 0.f)*w2v.w;
  #pragma unroll
  for (int off = 16; off >= 1; off >>= 1)
    p0 += __shfl_xor(p0, off, 64);
  if (l == 0){
    float a = p0 + b2[0];
    att[(size_t)wave*2 + h] = a;
    atomicMax(m_enc + (size_t)i*2 + h, encf(a));
    if (h == 0) atomicAdd(deg + i, 1);
  }
}

// ---------- exp(a - m) and segment sum ----------
__global__ void edge_exp_kernel(const int* __restrict__ ei, const int* __restrict__ flag,
                                float* __restrict__ att, const unsigned int* __restrict__ m_enc,
                                float* __restrict__ s, int E0, int Nn){
  int t = blockIdx.x*blockDim.x + threadIdx.x;
  int E = 2*E0 + Nn;
  if (t >= 2*E) return;
  int e = t >> 1, h = t & 1;
  int is64 = *flag;
  int i;
  if (e < E0) i = eidx(ei,is64,(long long)E0+e);
  else if (e < 2*E0) i = eidx(ei,is64,e-E0);
  else i = e - 2*E0;
  i = min(max(i,0), Nn-1);
  float m = decf(m_enc[(size_t)i*2+h]);
  float ex = expf(att[t] - m);
  att[t] = ex;
  atomicAdd(s + (size_t)i*2+h, ex);
}

// ---------- exclusive prefix scan of deg -> off[0..N] ----------
__global__ __launch_bounds__(1024) void scan_kernel(const int* __restrict__ deg,
                                                    int* __restrict__ off, int N){
  __shared__ int wsum[16];
  __shared__ int carry_s;
  int tid = threadIdx.x, lane = tid & 63, w = tid >> 6;
  if (tid == 0) carry_s = 0;
  __syncthreads();
  for (int base = 0; base < N; base += 1024){
    int carry = carry_s;
    int v = (base + tid < N) ? deg[base + tid] : 0;
    int incl = v;
    #pragma unroll
    for (int o = 1; o < 64; o <<= 1){
      int t = __shfl_up(incl, o, 64);
      if (lane >= o) incl += t;
    }
    if (lane == 63) wsum[w] = incl;
    __syncthreads();
    if (w == 0 && lane < 16){
      int sv = wsum[lane];
      #pragma unroll
      for (int o = 1; o < 16; o <<= 1){
        int t = __shfl_up(sv, o, 64);
        if (lane >= o) sv += t;
      }
      wsum[lane] = sv;
    }
    __syncthreads();
    int wpref = (w == 0) ? 0 : wsum[w-1];
    if (base + tid < N) off[base + tid] = carry + wpref + incl - v;
    __syncthreads();
    if (tid == 1023) carry_s = carry + wsum[15];
    __syncthreads();
  }
  if (threadIdx.x == 0) off[N] = carry_s;
}

// ---------- scatter edges into CSR buckets with final alpha ----------
__global__ void scatter_kernel(const int* __restrict__ ei, const int* __restrict__ flag,
                               const float* __restrict__ att, const float* __restrict__ s,
                               const int* __restrict__ off, int* __restrict__ cursor,
                               int* __restrict__ bj, float2* __restrict__ bw, int E0, int Nn){
  int e = blockIdx.x*blockDim.x + threadIdx.x;
  int E = 2*E0 + Nn;
  if (e >= E) return;
  int is64 = *flag;
  int j, i;
  if (e < E0){ j = eidx(ei,is64,e); i = eidx(ei,is64,(long long)E0+e); }
  else if (e < 2*E0){ int t = e - E0; i = eidx(ei,is64,t); j = eidx(ei,is64,(long long)E0+t); }
  else { i = j = e - 2*E0; }
  i = min(max(i,0), Nn-1); j = min(max(j,0), Nn-1);
  float w0 = att[(size_t)e*2+0] / (s[(size_t)i*2+0] + 1e-16f);
  float w1 = att[(size_t)e*2+1] / (s[(size_t)i*2+1] + 1e-16f);
  int pos = atomicAdd(cursor + i, 1);
  int slot = off[i] + pos;
  bj[slot] = j;
  bw[slot] = make_float2(w0, w1);
}

// ---------- gather: one wave per destination node -> bf16 agg ----------
__global__ __launch_bounds__(256) void gather_kernel(
    const float* __restrict__ P, const int* __restrict__ bj, const float2* __restrict__ bw,
    const int* __restrict__ off, bf16_t* __restrict__ aggb, int Nn)
{
  int i = blockIdx.x * (blockDim.x >> 6) + (threadIdx.x >> 6);
  if (i >= Nn) return;
  int lane = threadIdx.x & 63;
  int h = lane >> 5, d = (lane & 31) * 4;
  int s0 = off[i], s1 = off[i+1];
  float4 acc = make_float4(0.f,0.f,0.f,0.f);
  for (int t = s0; t < s1; ++t){
    int j = bj[t];
    float2 w = bw[t];
    float a = h ? w.y : w.x;
    const float4 vv = *(const float4*)(P + (size_t)j*768 + 512 + h*128 + d);
    acc.x = fmaf(a, vv.x, acc.x);
    acc.y = fmaf(a, vv.y, acc.y);
    acc.z = fmaf(a, vv.z, acc.z);
    acc.w = fmaf(a, vv.w, acc.w);
  }
  bf16x4 ob = { (bf16_t)acc.x, (bf16_t)acc.y, (bf16_t)acc.z, (bf16_t)acc.w };
  *(bf16x4*)(aggb + (size_t)i*256 + h*128 + d) = ob;
}

// ---------- launch ----------
extern "C" void kernel_launch(void* const* d_in, const int* in_sizes, int n_in,
                              void* d_out, int out_size, void* d_ws, size_t ws_size,
                              hipStream_t stream)
{
  const float* x     = (const float*)d_in[0];
  const int*   ei    = (const int*)d_in[1];
  const float* Wkqv  = (const float*)d_in[2];
  const float* bkqv  = (const float*)d_in[3];
  const float* W1    = (const float*)d_in[4];
  const float* b1    = (const float*)d_in[5];
  const float* W2    = (const float*)d_in[6];
  const float* b2    = (const float*)d_in[7];
  const float* Wout  = (const float*)d_in[8];
  const float* bout  = (const float*)d_in[9];
  float* out = (float*)d_out;

  const int N  = in_sizes[0] / EMB;   // 50000
  const int E0 = in_sizes[1] / 2;     // 100000
  const int E  = 2*E0 + N;            // 250000

  // workspace layout (fp32-word offsets; every buffer 16B-aligned)
  float* base = (float*)d_ws;
  bf16_t* WcombT = (bf16_t*)base;                       // 768*256 bf16 = 98304 w
  float*  bcomb  = base + 98304;                        // 768 w
  bf16_t* WoutT  = (bf16_t*)(base + 98304 + 768);       // 256*256 bf16 = 32768 w
  bf16_t* xb     = (bf16_t*)(base + 131840);            // N*256 bf16 = 6.4M w
  float*  P      = base + 131840 + 6400000;             // N*768 fp32
  bf16_t* aggb   = (bf16_t*)(P + (size_t)N*768);        // N*256 bf16
  float*  att    = (float*)(aggb + (size_t)N*256);      // E*2
  unsigned int* m_enc = (unsigned int*)(att + (size_t)E*2); // N*2
  float* svec  = (float*)(m_enc + (size_t)N*2);         // N*2
  int* deg     = (int*)(svec + (size_t)N*2);            // N
  int* flag    = deg + N;                               // 1
  int* off     = flag + 1;                              // N+1
  int* cursor  = off + (N+1);                           // N
  int* bj      = cursor + N;                            // E
  float2* bw   = (float2*)(bj + E + 1);                 // E float2 (8B aligned)

  hipMemsetAsync(m_enc, 0, ((size_t)N*4 + N + 1)*sizeof(int), stream); // m_enc,svec,deg,flag
  hipMemsetAsync(cursor, 0, (size_t)N*sizeof(int), stream);

  detect_kernel<<<1,1,0,stream>>>(ei, flag);
  cvt_x_kernel<<<((N*EMB/4)+255)/256,256,0,stream>>>(x, xb, N*EMB/4);
  prep_weights<<<dim3(3,257),256,0,stream>>>(Wkqv, bkqv, W1, WcombT, bcomb);
  prep_wout<<<256,256,0,stream>>>(Wout, WoutT);

  {
    dim3 grid(768/128, (N+127)/128);
    mfma_gemm<0><<<grid,256,0,stream>>>(xb, WcombT, bcomb, P, N, 768, 256, nullptr, nullptr);
  }
  {
    int blocks = (E + 3) / 4;
    edge_score_kernel<<<blocks,256,0,stream>>>(P, ei, b1, W2, b2, att, m_enc, deg, flag, E0, N);
    edge_exp_kernel<<<(2*E+255)/256,256,0,stream>>>(ei, flag, att, m_enc, svec, E0, N);
    scan_kernel<<<1,1024,0,stream>>>(deg, off, N);
    scatter_kernel<<<(E+255)/256,256,0,stream>>>(ei, flag, att, svec, off, cursor, bj, bw, E0, N);
    gather_kernel<<<(N+3)/4,256,0,stream>>>(P, bj, bw, off, aggb, N);
  }
  {
    dim3 grid(EMB/128, (N+127)/128);
    mfma_gemm<1><<<grid,256,0,stream>>>(aggb, WoutT, bout, out, N, EMB, 256, deg, x);
  }
}

// Round 4
// 354.649 us; speedup vs baseline: 3.8809x; 1.2415x over previous
//
#include <hip/hip_runtime.h>
#include <hip/hip_bf16.h>

#define EMB 256
#define HD 128

typedef __bf16 bf16_t;
typedef __attribute__((ext_vector_type(8))) __bf16 bf16x8;
typedef __attribute__((ext_vector_type(4))) __bf16 bf16x4;
typedef __attribute__((ext_vector_type(4))) float floatx4;

// ---------- helpers ----------
__device__ __forceinline__ int eidx(const int* __restrict__ p, int is64, long long k){
  return is64 ? p[2*k] : p[(int)k];
}
// async global->LDS, 16B per lane; lptr is WAVE-UNIFORM base, data lands at lptr + lane*16
__device__ __forceinline__ void async_load16(const void* g, void* l){
  __builtin_amdgcn_global_load_lds(
      (const __attribute__((address_space(1))) unsigned int*)g,
      (__attribute__((address_space(3))) unsigned int*)l,
      16, 0, 0);
}
__device__ __forceinline__ float4 cvt4(bf16x4 v){
  return make_float4((float)v.x, (float)v.y, (float)v.z, (float)v.w);
}

// ---------- dtype detect ----------
__global__ void detect_kernel(const int* __restrict__ ei, int* __restrict__ flag){
  int z = (ei[1]==0) + (ei[3]==0) + (ei[5]==0) + (ei[7]==0);
  *flag = (z == 4) ? 1 : 0;
}

// ---------- x -> bf16 ----------
__global__ void cvt_x_kernel(const float* __restrict__ x, bf16_t* __restrict__ xb, int n4){
  int t = blockIdx.x*blockDim.x + threadIdx.x;
  if (t >= n4) return;
  const float4 v = *(const float4*)(x + (size_t)t*4);
  bf16x4 o = { (bf16_t)v.x, (bf16_t)v.y, (bf16_t)v.z, (bf16_t)v.w };
  *(bf16x4*)(xb + (size_t)t*4) = o;
}

// ---------- fold W1 into Wkqv; emit TRANSPOSED bf16 WcombT[768][256] + fp32 bcomb[768] ----------
__global__ void prep_weights(const float* __restrict__ Wkqv, const float* __restrict__ bkqv,
                             const float* __restrict__ W1,
                             bf16_t* __restrict__ WcombT, float* __restrict__ bcomb){
  int n = blockIdx.x * blockDim.x + threadIdx.x;   // 0..767 (output col)
  int c = blockIdx.y;                              // 0..256 (k index; 256 = bias)
  if (n >= 768) return;
  const float rs = rsqrtf(128.0f);
  bool isBias = (c == 256);
  const float* arow = isBias ? bkqv : (Wkqv + (size_t)c*768);
  float val;
  if (n < 512){
    bool isQ = (n < 256);
    int nn = isQ ? n : (n - 256);
    int h = nn >> 7, d = nn & 127;
    int srcoff = isQ ? (h*128) : (256 + h*128);
    int w1off  = isQ ? 128 : 0;
    float s = 0.f;
    for (int t = 0; t < 128; ++t)
      s = fmaf(arow[srcoff + t], W1[(size_t)(w1off + t)*128 + d], s);
    val = isQ ? s : s * rs;
  } else {
    val = arow[512 + (n - 512)];
  }
  if (isBias) bcomb[n] = val;
  else        WcombT[(size_t)n*256 + c] = (bf16_t)val;
}

// ---------- Wout -> transposed bf16 WoutT[256][256] ----------
__global__ void prep_wout(const float* __restrict__ W, bf16_t* __restrict__ Wt){
  int t = blockIdx.x*blockDim.x + threadIdx.x;  // 65536
  int n = t & 255, c = t >> 8;
  Wt[(size_t)n*256 + c] = (bf16_t)W[(size_t)c*256 + n];
}

// ---------- degree count over the 2*E0 non-self edges (dst side) ----------
__global__ void deg_kernel(const int* __restrict__ ei, const int* __restrict__ flag,
                           int* __restrict__ deg, int E0, int Nn){
  int t = blockIdx.x*blockDim.x + threadIdx.x;
  if (t >= 2*E0) return;
  int is64 = *flag;
  int i = (t < E0) ? eidx(ei,is64,(long long)E0+t) : eidx(ei,is64,t-E0);
  i = min(max(i,0), Nn-1);
  atomicAdd(deg + i, 1);
}

// ---------- exclusive prefix scan of (deg+1) -> off[0..N] (self-loop slot included) ----------
__global__ __launch_bounds__(1024) void scan_kernel(const int* __restrict__ deg,
                                                    int* __restrict__ off, int N){
  __shared__ int wsum[16];
  __shared__ int carry_s;
  int tid = threadIdx.x, lane = tid & 63, w = tid >> 6;
  if (tid == 0) carry_s = 0;
  __syncthreads();
  for (int base = 0; base < N; base += 1024){
    int carry = carry_s;
    int v = (base + tid < N) ? (deg[base + tid] + 1) : 0;
    int incl = v;
    #pragma unroll
    for (int o = 1; o < 64; o <<= 1){
      int t = __shfl_up(incl, o, 64);
      if (lane >= o) incl += t;
    }
    if (lane == 63) wsum[w] = incl;
    __syncthreads();
    if (w == 0 && lane < 16){
      int sv = wsum[lane];
      #pragma unroll
      for (int o = 1; o < 16; o <<= 1){
        int t = __shfl_up(sv, o, 64);
        if (lane >= o) sv += t;
      }
      wsum[lane] = sv;
    }
    __syncthreads();
    int wpref = (w == 0) ? 0 : wsum[w-1];
    if (base + tid < N) off[base + tid] = carry + wpref + incl - v;
    __syncthreads();
    if (tid == 1023) carry_s = carry + wsum[15];
    __syncthreads();
  }
  if (threadIdx.x == 0) off[N] = carry_s;
}

// ---------- scatter source index j into CSR buckets (incl. self-loops) ----------
__global__ void scatter_kernel(const int* __restrict__ ei, const int* __restrict__ flag,
                               const int* __restrict__ off, int* __restrict__ cursor,
                               int* __restrict__ bj, int E0, int Nn){
  int e = blockIdx.x*blockDim.x + threadIdx.x;
  int E = 2*E0 + Nn;
  if (e >= E) return;
  int is64 = *flag;
  int j, i;
  if (e < E0){ j = eidx(ei,is64,e); i = eidx(ei,is64,(long long)E0+e); }
  else if (e < 2*E0){ int t = e - E0; i = eidx(ei,is64,t); j = eidx(ei,is64,(long long)E0+t); }
  else { i = j = e - 2*E0; }
  i = min(max(i,0), Nn-1); j = min(max(j,0), Nn-1);
  int pos = atomicAdd(cursor + i, 1);
  bj[off[i] + pos] = j;
}

// ---------- bf16 MFMA GEMM: C = A[M,K] @ Bt[N,K]^T + epilogue ----------
// Tile 128x128x32, 4 waves, each wave 64x64 via 4x4 MFMA 16x16x32.
// LDS fragment-ordered; staged via global_load_lds width 16.
// MODE 0: C(bf16) = AB + bias[n]
// MODE 1: C(fp32) = relu(AB + (deg[m]+1)*bias[n]) + xres[m*N+n]
template<int MODE, typename OutT>
__global__ __launch_bounds__(256) void mfma_gemm(
    const bf16_t* __restrict__ A, const bf16_t* __restrict__ Bt,
    const float* __restrict__ bias, OutT* __restrict__ C,
    int M, int N, int K,
    const int* __restrict__ deg, const float* __restrict__ xres)
{
  __shared__ bf16_t As[128*32];
  __shared__ bf16_t Bs[128*32];
  const int tid = threadIdx.x;
  const int wave = tid >> 6, lane = tid & 63;
  const int m0 = blockIdx.y * 128, n0 = blockIdx.x * 128;
  const int wm = (wave >> 1) * 64;
  const int wn = (wave & 1) * 64;
  const int row16 = lane & 15, quad = lane >> 4;

  floatx4 acc[4][4];
  #pragma unroll
  for (int a=0;a<4;++a)
    #pragma unroll
    for (int b=0;b<4;++b) acc[a][b] = (floatx4){0.f,0.f,0.f,0.f};

  for (int k0 = 0; k0 < K; k0 += 32){
    #pragma unroll
    for (int s = 0; s < 2; ++s){
      int f = wave*2 + s;
      int gm = m0 + f*16 + row16; gm = min(gm, M-1);
      async_load16(A  + (size_t)gm*K + k0 + quad*8, (char*)As + f*1024);
      int gn = n0 + f*16 + row16;          // N multiple of 128
      async_load16(Bt + (size_t)gn*K + k0 + quad*8, (char*)Bs + f*1024);
    }
    __syncthreads();
    bf16x8 af[4], bfr[4];
    #pragma unroll
    for (int t = 0; t < 4; ++t){
      af[t]  = *(const bf16x8*)((const char*)As + ((wm>>4)+t)*1024 + lane*16);
      bfr[t] = *(const bf16x8*)((const char*)Bs + ((wn>>4)+t)*1024 + lane*16);
    }
    #pragma unroll
    for (int mt=0;mt<4;++mt)
      #pragma unroll
      for (int nt=0;nt<4;++nt)
        acc[mt][nt] = __builtin_amdgcn_mfma_f32_16x16x32_bf16(af[mt], bfr[nt], acc[mt][nt], 0,0,0);
    __syncthreads();
  }

  // epilogue: C/D layout col=lane&15, row=quad*4+reg
  #pragma unroll
  for (int mt=0;mt<4;++mt){
    #pragma unroll
    for (int r=0;r<4;++r){
      int m = m0 + wm + mt*16 + quad*4 + r;
      if (m >= M) continue;
      float dg = (MODE==1) ? (float)(deg[m]+1) : 0.f;
      #pragma unroll
      for (int nt=0;nt<4;++nt){
        int n = n0 + wn + nt*16 + row16;
        float v = acc[mt][nt][r];
        if (MODE == 0){
          v += bias[n];
        } else {
          v = fmaxf(v + dg*bias[n], 0.f) + xres[(size_t)m*N + n];
        }
        C[(size_t)m*N + n] = (OutT)v;
      }
    }
  }
}

// ---------- fused attention: score + online softmax + aggregate, one wave per node ----------
__global__ __launch_bounds__(256) void fused_attn_kernel(
    const bf16_t* __restrict__ P, const int* __restrict__ bj, const int* __restrict__ off,
    const float* __restrict__ b1, const float* __restrict__ W2, const float* __restrict__ b2,
    bf16_t* __restrict__ aggb, int Nn)
{
  int i = blockIdx.x * (blockDim.x >> 6) + (threadIdx.x >> 6);
  if (i >= Nn) return;
  int lane = threadIdx.x & 63;
  int h = lane >> 5, d = (lane & 31) * 4;      // head, elem offset within head

  const float4 qv  = cvt4(*(const bf16x4*)(P + (size_t)i*768 + h*128 + d));
  const float4 b1v = *(const float4*)(b1 + d);
  const float4 w2v = *(const float4*)(W2 + d);
  const float b2v  = b2[0];

  float m = -3.0e38f, s = 0.f;
  float4 acc = make_float4(0.f,0.f,0.f,0.f);
  int s0 = off[i], s1 = off[i+1];
  for (int t = s0; t < s1; ++t){
    int j = bj[t];
    const float4 kv = cvt4(*(const bf16x4*)(P + (size_t)j*768 + 256 + h*128 + d));
    const float4 vv = cvt4(*(const bf16x4*)(P + (size_t)j*768 + 512 + h*128 + d));
    float p = fmaxf(qv.x+kv.x+b1v.x, 0.f)*w2v.x
            + fmaxf(qv.y+kv.y+b1v.y, 0.f)*w2v.y
            + fmaxf(qv.z+kv.z+b1v.z, 0.f)*w2v.z
            + fmaxf(qv.w+kv.w+b1v.w, 0.f)*w2v.w;
    // reduce across the 32-lane half-wave (bit5 = head, untouched)
    #pragma unroll
    for (int o = 16; o >= 1; o >>= 1)
      p += __shfl_xor(p, o, 64);
    float a = p + b2v;
    float mn = fmaxf(m, a);
    float sc = __expf(m - mn);
    float e  = __expf(a - mn);
    s = s*sc + e;
    acc.x = fmaf(acc.x, sc, e*vv.x);
    acc.y = fmaf(acc.y, sc, e*vv.y);
    acc.z = fmaf(acc.z, sc, e*vv.z);
    acc.w = fmaf(acc.w, sc, e*vv.w);
    m = mn;
  }
  float inv = 1.f / (s + 1e-16f);
  bf16x4 ob = { (bf16_t)(acc.x*inv), (bf16_t)(acc.y*inv), (bf16_t)(acc.z*inv), (bf16_t)(acc.w*inv) };
  *(bf16x4*)(aggb + (size_t)i*256 + h*128 + d) = ob;
}

// ---------- launch ----------
extern "C" void kernel_launch(void* const* d_in, const int* in_sizes, int n_in,
                              void* d_out, int out_size, void* d_ws, size_t ws_size,
                              hipStream_t stream)
{
  const float* x     = (const float*)d_in[0];
  const int*   ei    = (const int*)d_in[1];
  const float* Wkqv  = (const float*)d_in[2];
  const float* bkqv  = (const float*)d_in[3];
  const float* W1    = (const float*)d_in[4];
  const float* b1    = (const float*)d_in[5];
  const float* W2    = (const float*)d_in[6];
  const float* b2    = (const float*)d_in[7];
  const float* Wout  = (const float*)d_in[8];
  const float* bout  = (const float*)d_in[9];
  float* out = (float*)d_out;

  const int N  = in_sizes[0] / EMB;   // 50000
  const int E0 = in_sizes[1] / 2;     // 100000
  const int E  = 2*E0 + N;            // 250000

  // workspace layout (fp32-word offsets; all 16B-aligned)
  float* base = (float*)d_ws;
  bf16_t* WcombT = (bf16_t*)base;                       // 768*256 bf16 = 98304 w
  float*  bcomb  = base + 98304;                        // 768 w
  bf16_t* WoutT  = (bf16_t*)(base + 98304 + 768);       // 256*256 bf16 = 32768 w
  bf16_t* xb     = (bf16_t*)(base + 131840);            // N*256 bf16
  bf16_t* Pb     = (bf16_t*)(base + 131840 + 6400000);  // N*768 bf16
  bf16_t* aggb   = (bf16_t*)(Pb + (size_t)N*768);       // N*256 bf16
  int* deg       = (int*)(aggb + (size_t)N*256);        // N
  int* cursor    = deg + N;                             // N
  int* flag      = cursor + N;                          // 1
  int* off       = flag + 1;                            // N+1
  int* bj        = off + (N+1);                         // E

  hipMemsetAsync(deg, 0, (size_t)2*N*sizeof(int), stream);  // deg + cursor

  detect_kernel<<<1,1,0,stream>>>(ei, flag);
  cvt_x_kernel<<<((N*EMB/4)+255)/256,256,0,stream>>>(x, xb, N*EMB/4);
  prep_weights<<<dim3(3,257),256,0,stream>>>(Wkqv, bkqv, W1, WcombT, bcomb);
  prep_wout<<<256,256,0,stream>>>(Wout, WoutT);

  deg_kernel<<<(2*E0+255)/256,256,0,stream>>>(ei, flag, deg, E0, N);
  scan_kernel<<<1,1024,0,stream>>>(deg, off, N);
  scatter_kernel<<<(E+255)/256,256,0,stream>>>(ei, flag, off, cursor, bj, E0, N);

  {
    dim3 grid(768/128, (N+127)/128);
    mfma_gemm<0, bf16_t><<<grid,256,0,stream>>>(xb, WcombT, bcomb, Pb, N, 768, 256, nullptr, nullptr);
  }
  fused_attn_kernel<<<(N+3)/4,256,0,stream>>>(Pb, bj, off, b1, W2, b2, aggb, N);
  {
    dim3 grid(EMB/128, (N+127)/128);
    mfma_gemm<1, float><<<grid,256,0,stream>>>(aggb, WoutT, bout, out, N, EMB, 256, deg, x);
  }
}